// Round 9
// baseline (2241.541 us; speedup 1.0000x reference)
//
#include <hip/hip_runtime.h>

#define L_ 2
#define T_ 512
#define B_ 128
#define F_ 4
#define H_ 256
#define QSIGN_MASK 0x5390
#define NIT 514   // iterations: layer-0 steps 0..511, layer-1 lags by 2

typedef __attribute__((ext_vector_type(8))) short short8;
typedef __attribute__((ext_vector_type(4))) float f32x4;

__device__ __forceinline__ unsigned f2bf(float f) {
  unsigned u = __float_as_uint(f);
  return (u + 0x7fff + ((u >> 16) & 1)) >> 16;
}
__device__ __forceinline__ float fast_sigmoid(float x) { return 1.f / (1.f + __expf(-x)); }
__device__ __forceinline__ float fast_tanh(float x) {
  float a = fabsf(x), e = __expf(2.f * a);
  return copysignf(1.f - 2.f / (e + 1.f), x);
}
__device__ __forceinline__ unsigned long long pack4bf(float a, float b, float c, float d) {
  return (unsigned long long)f2bf(a)
       | ((unsigned long long)f2bf(b) << 16)
       | ((unsigned long long)f2bf(c) << 32)
       | ((unsigned long long)f2bf(d) << 48);
}

union FragU { short8 v; uint4 u; unsigned w[4]; };

// Grid = 32 WGs x 576 threads (9 waves); WG handles BOTH layers for 4 batches.
// Waves 0-3: layer-0 compute (wave w -> u-cols [16w,16w+16)). Wave 4: layer-0
// projection -> sh_q1 (layer-1's x), via MFMA, all in LDS. Waves 5-8: layer-1
// compute, lagging 2 iterations. ONE barrier per iteration; the loop touches
// NO global memory (x preloaded to LDS; output written in epilogue).
// Compute MFMA: M rows = b*4+q (b=quad, q=reg), N = u16, K=256 over (d,p);
// 4 accumulator sets (one per gate) -> LSTM update fully in-lane, zero shuffles.
__launch_bounds__(576, 1)
__global__ void qlstm_one(const float* __restrict__ x_in,
                          const float* __restrict__ uhr, const float* __restrict__ uhi,
                          const float* __restrict__ uhj, const float* __restrict__ uhk,
                          const float* __restrict__ wxr, const float* __restrict__ wxi,
                          const float* __restrict__ wxj, const float* __restrict__ wxk,
                          const float* __restrict__ wxb_all,
                          const float* __restrict__ fcw_all, const float* __restrict__ fcb_all,
                          float* __restrict__ out_final)
{
  __shared__ unsigned long long sh_x0[T_][4];               // 16 KB: x, bf16x4 packed
  __shared__ unsigned long long sh_q1[T_][4];               // 16 KB: layer-0 outputs
  __shared__ __align__(16) unsigned short sh_h[2][2][4][272]; // 8.5 KB: h per layer, dbuf

  const int t    = threadIdx.x;
  const int bg0  = blockIdx.x * 4;
  const int wv   = t >> 6;
  const int lane = t & 63;
  const int quad = lane >> 4;
  const int sub  = lane & 15;

  // ---- preload x into LDS (packed bf16x4) + zero h ----
  for (int i = t; i < T_ * 4; i += 576) {
    const int b = i >> 9, s = i & 511;
    float4 xv = *(const float4*)(x_in + (size_t)((bg0 + b) * T_ + s) * F_);
    sh_x0[s][b] = pack4bf(xv.x, xv.y, xv.z, xv.w);
  }
  for (int i = t; i < 2 * 2 * 4 * 272; i += 576) ((unsigned short*)sh_h)[i] = 0;

  if (wv == 4) {
    // ================= PROJECTION WAVE =================
    // fw^T A-frags (layer 0): A[m=f][k] = fw[k][f], rows 4-15 zero
    FragU Af[8];
    #pragma unroll
    for (int ks = 0; ks < 8; ++ks) {
      FragU f;
      #pragma unroll
      for (int j = 0; j < 8; ++j) {
        const int k = ks * 32 + quad * 8 + j;
        f.v[j] = (sub < 4) ? (short)f2bf(fcw_all[k * 4 + sub]) : (short)0;
      }
      Af[ks] = f;
    }
    const float fb0 = fcb_all[0], fb1 = fcb_all[1], fb2 = fcb_all[2], fb3 = fcb_all[3];
    const int bl = sub & 3;
    __syncthreads();

    for (int i = 0; i < NIT; ++i) {
      const int sp = i - 1;              // project layer-0 h[sp]
      if (sp >= 0 && sp < T_) {
        const char* hp = (const char*)&sh_h[0][sp & 1][0][0];
        f32x4 pa = {fb0, fb1, fb2, fb3};
        #pragma unroll
        for (int ks = 0; ks < 8; ++ks) {
          FragU Bh;
          Bh.u = *(const uint4*)(hp + bl * 544 + ((ks * 32 + quad * 8) << 1));
          pa = __builtin_amdgcn_mfma_f32_16x16x32_bf16(Af[ks].v, Bh.v, pa, 0, 0, 0);
        }
        if (lane < 4) {                  // all 4 components in-reg; batch = lane
          float p0 = pa[0], p1 = pa[1], p2 = pa[2], p3 = pa[3];
          float inv = 1.f / fmaxf(sqrtf(p0*p0 + p1*p1 + p2*p2 + p3*p3), 1e-12f);
          sh_q1[sp][lane] = pack4bf(p0 * inv, p1 * inv, p2 * inv, p3 * inv);
        }
      }
      __syncthreads();
    }

    // ---- epilogue: layer-1 projection of h[T-1] -> output ----
    const float* fw1 = fcw_all + H_ * F_;
    const float* fc1 = fcb_all + F_;
    #pragma unroll
    for (int ks = 0; ks < 8; ++ks) {
      FragU f;
      #pragma unroll
      for (int j = 0; j < 8; ++j) {
        const int k = ks * 32 + quad * 8 + j;
        f.v[j] = (sub < 4) ? (short)f2bf(fw1[k * 4 + sub]) : (short)0;
      }
      Af[ks] = f;
    }
    const char* hp = (const char*)&sh_h[1][(T_ - 1) & 1][0][0];
    f32x4 pa = {fc1[0], fc1[1], fc1[2], fc1[3]};
    #pragma unroll
    for (int ks = 0; ks < 8; ++ks) {
      FragU Bh;
      Bh.u = *(const uint4*)(hp + bl * 544 + ((ks * 32 + quad * 8) << 1));
      pa = __builtin_amdgcn_mfma_f32_16x16x32_bf16(Af[ks].v, Bh.v, pa, 0, 0, 0);
    }
    if (lane < 4) {
      float p0 = pa[0], p1 = pa[1], p2 = pa[2], p3 = pa[3];
      float inv = 1.f / fmaxf(sqrtf(p0*p0 + p1*p1 + p2*p2 + p3*p3), 1e-12f);
      *(float4*)(out_final + (bg0 + lane) * F_) =
          make_float4(p0 * inv, p1 * inv, p2 * inv, p3 * inv);
    }
  } else {
    // ================= COMPUTE WAVES =================
    const int lyr = (wv < 4) ? 0 : 1;
    const int cw  = (wv < 4) ? wv : wv - 5;
    const int lag = lyr ? 2 : 0;
    const int u   = cw * 16 + sub;   // B n-col / D col
    const int ba  = sub >> 2;        // A-side row -> batch
    const int qa  = sub & 3;         // A-side row -> q

    // persistent B fragments [g][ks] + x-weights + bias
    FragU Bf[32], Bx[4];
    float bv[4][4];
    {
      const float* Cc[4] = {uhr, uhi, uhj, uhk};
      const float* Xc[4] = {wxr, wxi, wxj, wxk};
      const float* wb = wxb_all + lyr * 4 * H_;
      #pragma unroll
      for (int g = 0; g < 4; ++g) {
        #pragma unroll
        for (int ks = 0; ks < 8; ++ks) {
          const int d  = ks >> 1;
          const int pp = (ks & 1) * 32 + quad * 8;
          const float* src = Cc[d] + (size_t)((lyr * 4 + g) * 64 + pp) * 64 + u;
          FragU f;
          #pragma unroll
          for (int j = 0; j < 8; ++j) f.v[j] = (short)f2bf(src[j * 64]);
          Bf[g * 8 + ks] = f;
        }
        FragU fx; fx.w[0] = 0; fx.w[1] = 0; fx.w[2] = 0; fx.w[3] = 0;
        if (quad == 0) {
          unsigned e0 = f2bf(Xc[0][(lyr * 4 + g) * 64 + u]);
          unsigned e1 = f2bf(Xc[1][(lyr * 4 + g) * 64 + u]);
          unsigned e2 = f2bf(Xc[2][(lyr * 4 + g) * 64 + u]);
          unsigned e3 = f2bf(Xc[3][(lyr * 4 + g) * 64 + u]);
          fx.w[0] = e0 | (e1 << 16);
          fx.w[1] = e2 | (e3 << 16);
        }
        Bx[g] = fx;
        #pragma unroll
        for (int r = 0; r < 4; ++r) bv[g][r] = wb[g * 256 + r * 64 + u];
      }
    }
    // sign masks (a = qa^d) and A-read byte offsets
    unsigned smask[4], smx[4];
    int xsh[4], aoff[8];
    #pragma unroll
    for (int d = 0; d < 4; ++d) {
      const int a = qa ^ d;
      const bool neg = (QSIGN_MASK >> (a * 4 + qa)) & 1;
      smask[d] = neg ? 0x80008000u : 0u;
      smx[d]   = neg ? 0x8000u : 0u;
      xsh[d]   = 16 * a;
    }
    #pragma unroll
    for (int ks = 0; ks < 8; ++ks)
      aoff[ks] = ba * 544 + (((qa ^ (ks >> 1)) * 64 + (ks & 1) * 32 + quad * 8) << 1);

    char* hbase = (char*)&sh_h[lyr][0][0][0];
    const unsigned long long (*xsrc)[4] = lyr ? sh_q1 : sh_x0;
    float cs[4] = {0.f, 0.f, 0.f, 0.f};
    __syncthreads();

    for (int i = 0; i < NIT; ++i) {
      const int s = i - lag;
      if (s >= 0 && s < T_) {
        const char* hp = hbase + ((s + 1) & 1) * 2176;   // h[s-1]
        // x A-frag: k=d, value = sign(qa,d)*x[b][qa^d]
        unsigned long long xq = xsrc[s][ba];
        FragU Ax; Ax.w[0] = 0; Ax.w[1] = 0; Ax.w[2] = 0; Ax.w[3] = 0;
        if (quad == 0) {
          unsigned e0 = ((unsigned)(xq >> xsh[0]) & 0xffffu) ^ smx[0];
          unsigned e1 = ((unsigned)(xq >> xsh[1]) & 0xffffu) ^ smx[1];
          unsigned e2 = ((unsigned)(xq >> xsh[2]) & 0xffffu) ^ smx[2];
          unsigned e3 = ((unsigned)(xq >> xsh[3]) & 0xffffu) ^ smx[3];
          Ax.w[0] = e0 | (e1 << 16);
          Ax.w[1] = e2 | (e3 << 16);
        }
        f32x4 acc0 = {bv[0][0], bv[0][1], bv[0][2], bv[0][3]};
        f32x4 acc1 = {bv[1][0], bv[1][1], bv[1][2], bv[1][3]};
        f32x4 acc2 = {bv[2][0], bv[2][1], bv[2][2], bv[2][3]};
        f32x4 acc3 = {bv[3][0], bv[3][1], bv[3][2], bv[3][3]};
        acc0 = __builtin_amdgcn_mfma_f32_16x16x32_bf16(Ax.v, Bx[0].v, acc0, 0, 0, 0);
        acc1 = __builtin_amdgcn_mfma_f32_16x16x32_bf16(Ax.v, Bx[1].v, acc1, 0, 0, 0);
        acc2 = __builtin_amdgcn_mfma_f32_16x16x32_bf16(Ax.v, Bx[2].v, acc2, 0, 0, 0);
        acc3 = __builtin_amdgcn_mfma_f32_16x16x32_bf16(Ax.v, Bx[3].v, acc3, 0, 0, 0);
        #pragma unroll
        for (int ks = 0; ks < 8; ++ks) {
          FragU A;
          A.u = *(const uint4*)(hp + aoff[ks]);
          const unsigned m = smask[ks >> 1];
          A.w[0] ^= m; A.w[1] ^= m; A.w[2] ^= m; A.w[3] ^= m;
          acc0 = __builtin_amdgcn_mfma_f32_16x16x32_bf16(A.v, Bf[0 * 8 + ks].v, acc0, 0, 0, 0);
          acc1 = __builtin_amdgcn_mfma_f32_16x16x32_bf16(A.v, Bf[1 * 8 + ks].v, acc1, 0, 0, 0);
          acc2 = __builtin_amdgcn_mfma_f32_16x16x32_bf16(A.v, Bf[2 * 8 + ks].v, acc2, 0, 0, 0);
          acc3 = __builtin_amdgcn_mfma_f32_16x16x32_bf16(A.v, Bf[3 * 8 + ks].v, acc3, 0, 0, 0);
        }
        // fully in-lane gates: b=quad, col = r*64+u
        char* hw = hbase + (s & 1) * 2176 + quad * 544;
        #pragma unroll
        for (int r = 0; r < 4; ++r) {
          float fg = fast_sigmoid(acc0[r]);
          float ig = fast_sigmoid(acc1[r]);
          float og = fast_sigmoid(acc2[r]);
          float cv = fast_tanh(acc3[r]);
          cs[r] = ig * cv + fg * cs[r];
          float h = og * fast_tanh(cs[r]);
          *(unsigned short*)(hw + ((r * 64 + u) << 1)) = (unsigned short)f2bf(h);
        }
      }
      __syncthreads();
    }
  }
}

extern "C" void kernel_launch(void* const* d_in, const int* in_sizes, int n_in,
                              void* d_out, int out_size, void* d_ws, size_t ws_size,
                              hipStream_t stream) {
  const float* x   = (const float*)d_in[0];
  const float* wxr = (const float*)d_in[1];
  const float* wxi = (const float*)d_in[2];
  const float* wxj = (const float*)d_in[3];
  const float* wxk = (const float*)d_in[4];
  const float* wxb = (const float*)d_in[5];
  const float* uhr = (const float*)d_in[6];
  const float* uhi = (const float*)d_in[7];
  const float* uhj = (const float*)d_in[8];
  const float* uhk = (const float*)d_in[9];
  const float* fcw = (const float*)d_in[10];
  const float* fcb = (const float*)d_in[11];
  float* out = (float*)d_out;

  qlstm_one<<<dim3(B_ / 4), dim3(576), 0, stream>>>(
      x, uhr, uhi, uhj, uhk, wxr, wxi, wxj, wxk, wxb, fcw, fcb, out);
}

// Round 10
// 945.085 us; speedup vs baseline: 2.3718x; 2.3718x over previous
//
#include <hip/hip_runtime.h>

#define L_ 2
#define T_ 512
#define B_ 128
#define F_ 4
#define H_ 256
#define QSIGN_MASK 0x5390

typedef __attribute__((ext_vector_type(8))) short short8;
typedef __attribute__((ext_vector_type(4))) float f32x4;

// Mailbox: layer-0 normalized output, per (t,b,f) one u32 = 0x10000 | bf16.
// Tag bit 16 guarantees nonzero. Zeroed every call (device globals persist).
__device__ unsigned g_mb[T_][B_][F_];

__global__ void zero_mb() {
  ((unsigned*)g_mb)[blockIdx.x * 256 + threadIdx.x] = 0u;
}

__device__ __forceinline__ unsigned f2bf(float f) {
  unsigned u = __float_as_uint(f);
  return (u + 0x7fff + ((u >> 16) & 1)) >> 16;
}
__device__ __forceinline__ float fast_sigmoid(float x) { return 1.f / (1.f + __expf(-x)); }
__device__ __forceinline__ float fast_tanh(float x) {
  float a = fabsf(x), e = __expf(2.f * a);
  return copysignf(1.f - 2.f / (e + 1.f), x);
}

union FragU { short8 v; uint4 u; unsigned w[4]; };

// Grid = 64 WGs x 256 threads (4 waves, 1 wave/SIMD -> 512-reg budget, no spills).
// blockIdx<32: layer-0 producer; else layer-1 consumer (same bg -> same XCD pair).
// All 4 waves are compute waves (wave w -> u-cols [16w,16w+16)). MFMA M rows =
// b*4+q, N = u16, one accumulator set per gate: LSTM update fully in-lane.
// Projection: in-lane partials (16 FMAs) + shfl_xor reduce over the 16-lane
// u-group -> sh_pp[wave][b][f]; wave 0 lanes 0-15 finalize NEXT iter (sum 4
// waves + bias, norm via 2 DPP shuffles) and publish 4B tagged-bf16 mailbox
// entries (producer) or final output (consumer epilogue).
// Producer x: whole sequence preloaded to LDS (16 KB) -> loop has only the
// 16-lane mailbox store as global traffic. Consumer polls slot i+4 at TOP.
__launch_bounds__(256, 1)
__global__ void qlstm_pipe(const float* __restrict__ x_in,
                           const float* __restrict__ uhr, const float* __restrict__ uhi,
                           const float* __restrict__ uhj, const float* __restrict__ uhk,
                           const float* __restrict__ wxr, const float* __restrict__ wxi,
                           const float* __restrict__ wxj, const float* __restrict__ wxk,
                           const float* __restrict__ wxb_all,
                           const float* __restrict__ fcw_all, const float* __restrict__ fcb_all,
                           float* __restrict__ out_final)
{
  __shared__ __align__(8)  unsigned short sh_x[T_][4][4];   // 16 KB bf16 x per (s,b,f)
  __shared__ __align__(16) unsigned short sh_h[2][4][272];  // 4.25 KB h dbuf
  __shared__ float sh_pp[2][4][4][4];                       // [parity][wave][b][f]

  const int t    = threadIdx.x;
  const int role = blockIdx.x >> 5;
  const int bg   = blockIdx.x & 31;
  const int bg0  = bg * 4;
  const int lyr  = role;
  const int wv   = t >> 6;
  const int lane = t & 63;
  const int quad = lane >> 4;
  const int sub  = lane & 15;

  for (int i = t; i < 2 * 4 * 272; i += 256) ((unsigned short*)sh_h)[i] = 0;

  if (role == 0) {
    // preload full x sequence (bf16-packed) into LDS
    for (int idx = t; idx < T_ * 4; idx += 256) {
      const int s = idx & (T_ - 1), b = idx >> 9;
      float4 xv = *(const float4*)(x_in + (size_t)((bg0 + b) * T_ + s) * F_);
      sh_x[s][b][0] = (unsigned short)f2bf(xv.x);
      sh_x[s][b][1] = (unsigned short)f2bf(xv.y);
      sh_x[s][b][2] = (unsigned short)f2bf(xv.z);
      sh_x[s][b][3] = (unsigned short)f2bf(xv.w);
    }
  } else if (t < 16) {
    // consumer prologue: slots 0..3
    const int b = t >> 2, f = t & 3;
    for (int slot = 0; slot < 4; ++slot) {
      unsigned v;
      while ((v = __hip_atomic_load(&g_mb[slot][bg0 + b][f], __ATOMIC_RELAXED,
                                    __HIP_MEMORY_SCOPE_AGENT)) == 0u)
        __builtin_amdgcn_s_sleep(1);
      sh_x[slot][b][f] = (unsigned short)v;
    }
  }

  // ---- per-wave compute constants ----
  const int u  = wv * 16 + sub;   // B n-col / D col
  const int ba = sub >> 2;        // A-side row -> batch
  const int qa = sub & 3;         // A-side row -> q

  FragU Bf[32], Bx[4];
  float bv[4][4];
  {
    const float* Cc[4] = {uhr, uhi, uhj, uhk};
    const float* Xc[4] = {wxr, wxi, wxj, wxk};
    const float* wb = wxb_all + lyr * 4 * H_;
    #pragma unroll
    for (int g = 0; g < 4; ++g) {
      #pragma unroll
      for (int ks = 0; ks < 8; ++ks) {
        const int d  = ks >> 1;
        const int pp = (ks & 1) * 32 + quad * 8;
        const float* src = Cc[d] + (size_t)((lyr * 4 + g) * 64 + pp) * 64 + u;
        FragU f;
        #pragma unroll
        for (int j = 0; j < 8; ++j) f.v[j] = (short)f2bf(src[j * 64]);
        Bf[g * 8 + ks] = f;
      }
      FragU fx; fx.w[0] = 0; fx.w[1] = 0; fx.w[2] = 0; fx.w[3] = 0;
      if (quad == 0) {
        unsigned e0 = f2bf(Xc[0][(lyr * 4 + g) * 64 + u]);
        unsigned e1 = f2bf(Xc[1][(lyr * 4 + g) * 64 + u]);
        unsigned e2 = f2bf(Xc[2][(lyr * 4 + g) * 64 + u]);
        unsigned e3 = f2bf(Xc[3][(lyr * 4 + g) * 64 + u]);
        fx.w[0] = e0 | (e1 << 16);
        fx.w[1] = e2 | (e3 << 16);
      }
      Bx[g] = fx;
      #pragma unroll
      for (int r = 0; r < 4; ++r) bv[g][r] = wb[g * 256 + r * 64 + u];
    }
  }
  unsigned smask[4], smx[4];
  int xsh[4], aoff[8];
  #pragma unroll
  for (int d = 0; d < 4; ++d) {
    const int a = qa ^ d;
    const bool neg = (QSIGN_MASK >> (a * 4 + qa)) & 1;
    smask[d] = neg ? 0x80008000u : 0u;
    smx[d]   = neg ? 0x8000u : 0u;
    xsh[d]   = 16 * a;
  }
  #pragma unroll
  for (int ks = 0; ks < 8; ++ks)
    aoff[ks] = ba * 544 + (((qa ^ (ks >> 1)) * 64 + (ks & 1) * 32 + quad * 8) << 1);

  // projection constants: lane covers h cols q*64+u, q=0..3
  float fwr[4][4];
  {
    const float* fw = fcw_all + lyr * H_ * F_;
    #pragma unroll
    for (int q = 0; q < 4; ++q)
      #pragma unroll
      for (int f = 0; f < 4; ++f) fwr[q][f] = fw[(q * 64 + u) * 4 + f];
  }
  const float fbl = (fcb_all + lyr * F_)[lane & 3];

  float cs[4] = {0.f, 0.f, 0.f, 0.f};
  char* hbase = (char*)sh_h;
  __syncthreads();

  for (int i = 0; i <= T_; ++i) {
    // ---- TOP: wave 0 lanes 0-15: finalize+publish (producer) / poll (consumer) ----
    if (wv == 0 && lane < 16) {
      const int b = lane >> 2, f = lane & 3;
      if (role == 0) {
        if (i >= 1) {
          const int par = (i - 1) & 1;
          float v = sh_pp[par][0][b][f] + sh_pp[par][1][b][f]
                  + sh_pp[par][2][b][f] + sh_pp[par][3][b][f] + fbl;
          float ss = v * v;
          ss += __shfl_xor(ss, 1, 64);
          ss += __shfl_xor(ss, 2, 64);
          float inv = 1.f / fmaxf(sqrtf(ss), 1e-12f);
          __hip_atomic_store(&g_mb[i - 1][bg0 + b][f], 0x10000u | f2bf(v * inv),
                             __ATOMIC_RELAXED, __HIP_MEMORY_SCOPE_AGENT);
        }
      } else {
        const int slot = i + 4;
        if (slot < T_) {
          unsigned v;
          while ((v = __hip_atomic_load(&g_mb[slot][bg0 + b][f], __ATOMIC_RELAXED,
                                        __HIP_MEMORY_SCOPE_AGENT)) == 0u)
            __builtin_amdgcn_s_sleep(1);
          sh_x[slot][b][f] = (unsigned short)v;
        }
      }
    }

    // ---- MIDDLE: recurrent MFMA + in-lane gates ----
    if (i < T_) {
      const char* hp = hbase + ((i + 1) & 1) * 2176;   // h[i-1]
      unsigned long long xq = *(const unsigned long long*)&sh_x[i][ba][0];
      FragU Ax; Ax.w[0] = 0; Ax.w[1] = 0; Ax.w[2] = 0; Ax.w[3] = 0;
      if (quad == 0) {
        unsigned e0 = ((unsigned)(xq >> xsh[0]) & 0xffffu) ^ smx[0];
        unsigned e1 = ((unsigned)(xq >> xsh[1]) & 0xffffu) ^ smx[1];
        unsigned e2 = ((unsigned)(xq >> xsh[2]) & 0xffffu) ^ smx[2];
        unsigned e3 = ((unsigned)(xq >> xsh[3]) & 0xffffu) ^ smx[3];
        Ax.w[0] = e0 | (e1 << 16);
        Ax.w[1] = e2 | (e3 << 16);
      }
      f32x4 acc0 = {bv[0][0], bv[0][1], bv[0][2], bv[0][3]};
      f32x4 acc1 = {bv[1][0], bv[1][1], bv[1][2], bv[1][3]};
      f32x4 acc2 = {bv[2][0], bv[2][1], bv[2][2], bv[2][3]};
      f32x4 acc3 = {bv[3][0], bv[3][1], bv[3][2], bv[3][3]};
      acc0 = __builtin_amdgcn_mfma_f32_16x16x32_bf16(Ax.v, Bx[0].v, acc0, 0, 0, 0);
      acc1 = __builtin_amdgcn_mfma_f32_16x16x32_bf16(Ax.v, Bx[1].v, acc1, 0, 0, 0);
      acc2 = __builtin_amdgcn_mfma_f32_16x16x32_bf16(Ax.v, Bx[2].v, acc2, 0, 0, 0);
      acc3 = __builtin_amdgcn_mfma_f32_16x16x32_bf16(Ax.v, Bx[3].v, acc3, 0, 0, 0);
      #pragma unroll
      for (int ks = 0; ks < 8; ++ks) {
        FragU A;
        A.u = *(const uint4*)(hp + aoff[ks]);
        const unsigned m = smask[ks >> 1];
        A.w[0] ^= m; A.w[1] ^= m; A.w[2] ^= m; A.w[3] ^= m;
        acc0 = __builtin_amdgcn_mfma_f32_16x16x32_bf16(A.v, Bf[0 * 8 + ks].v, acc0, 0, 0, 0);
        acc1 = __builtin_amdgcn_mfma_f32_16x16x32_bf16(A.v, Bf[1 * 8 + ks].v, acc1, 0, 0, 0);
        acc2 = __builtin_amdgcn_mfma_f32_16x16x32_bf16(A.v, Bf[2 * 8 + ks].v, acc2, 0, 0, 0);
        acc3 = __builtin_amdgcn_mfma_f32_16x16x32_bf16(A.v, Bf[3 * 8 + ks].v, acc3, 0, 0, 0);
      }
      // in-lane gates: b=quad, col = r*64+u
      char* hw = hbase + (i & 1) * 2176 + quad * 544;
      float hv[4];
      #pragma unroll
      for (int r = 0; r < 4; ++r) {
        float fg = fast_sigmoid(acc0[r]);
        float ig = fast_sigmoid(acc1[r]);
        float og = fast_sigmoid(acc2[r]);
        float cv = fast_tanh(acc3[r]);
        cs[r] = ig * cv + fg * cs[r];
        hv[r] = og * fast_tanh(cs[r]);
        *(unsigned short*)(hw + ((r * 64 + u) << 1)) = (unsigned short)f2bf(hv[r]);
      }
      // in-lane projection partial + intra-group reduce (producer always; consumer last)
      if (role == 0 || i == T_ - 1) {
        float p[4];
        #pragma unroll
        for (int f = 0; f < 4; ++f)
          p[f] = hv[0] * fwr[0][f] + hv[1] * fwr[1][f]
               + hv[2] * fwr[2][f] + hv[3] * fwr[3][f];
        #pragma unroll
        for (int f = 0; f < 4; ++f) {
          p[f] += __shfl_xor(p[f], 1, 64);
          p[f] += __shfl_xor(p[f], 2, 64);
          p[f] += __shfl_xor(p[f], 4, 64);
          p[f] += __shfl_xor(p[f], 8, 64);
        }
        if (sub == 0)
          *(float4*)&sh_pp[i & 1][wv][quad][0] = make_float4(p[0], p[1], p[2], p[3]);
      }
    }
    __syncthreads();
  }

  // ---- consumer epilogue: finalize projection of h[T-1] -> output ----
  if (role == 1 && wv == 0 && lane < 16) {
    const int b = lane >> 2, f = lane & 3;
    const int par = (T_ - 1) & 1;
    float v = sh_pp[par][0][b][f] + sh_pp[par][1][b][f]
            + sh_pp[par][2][b][f] + sh_pp[par][3][b][f] + fbl;
    float ss = v * v;
    ss += __shfl_xor(ss, 1, 64);
    ss += __shfl_xor(ss, 2, 64);
    float inv = 1.f / fmaxf(sqrtf(ss), 1e-12f);
    out_final[(bg0 + b) * F_ + f] = v * inv;
  }
}

extern "C" void kernel_launch(void* const* d_in, const int* in_sizes, int n_in,
                              void* d_out, int out_size, void* d_ws, size_t ws_size,
                              hipStream_t stream) {
  const float* x   = (const float*)d_in[0];
  const float* wxr = (const float*)d_in[1];
  const float* wxi = (const float*)d_in[2];
  const float* wxj = (const float*)d_in[3];
  const float* wxk = (const float*)d_in[4];
  const float* wxb = (const float*)d_in[5];
  const float* uhr = (const float*)d_in[6];
  const float* uhi = (const float*)d_in[7];
  const float* uhj = (const float*)d_in[8];
  const float* uhk = (const float*)d_in[9];
  const float* fcw = (const float*)d_in[10];
  const float* fcb = (const float*)d_in[11];
  float* out = (float*)d_out;

  zero_mb<<<dim3(T_ * B_ * F_ / 256), dim3(256), 0, stream>>>();
  qlstm_pipe<<<dim3(64), dim3(256), 0, stream>>>(
      x, uhr, uhi, uhj, uhk, wxr, wxi, wxj, wxk, wxb, fcw, fcb, out);
}

// Round 11
// 721.019 us; speedup vs baseline: 3.1089x; 1.3108x over previous
//
#include <hip/hip_runtime.h>

#define L_ 2
#define T_ 512
#define B_ 128
#define F_ 4
#define H_ 256
#define QSIGN_MASK 0x5390
#define KB_ 8          // mailbox batch (steps per publish/poll)

typedef __attribute__((ext_vector_type(8))) short short8;
typedef __attribute__((ext_vector_type(4))) float f32x4;

// Mailbox: layer-0 normalized output, bf16x4 packed per (t,b); norm-1 => at least
// one |comp| >= 0.5 => qword never 0. Zeroed every call.
__device__ unsigned long long g_mbq[T_][B_];

__global__ void zero_mb() {
  ((unsigned long long*)g_mbq)[blockIdx.x * 256 + threadIdx.x] = 0ull;
}

__device__ __forceinline__ unsigned f2bf(float f) {
  unsigned u = __float_as_uint(f);
  return (u + 0x7fff + ((u >> 16) & 1)) >> 16;
}
__device__ __forceinline__ float fast_sigmoid(float x) { return 1.f / (1.f + __expf(-x)); }
__device__ __forceinline__ float fast_tanh(float x) {
  float a = fabsf(x), e = __expf(2.f * a);
  return copysignf(1.f - 2.f / (e + 1.f), x);
}
__device__ __forceinline__ unsigned long long pack4bf(float a, float b, float c, float d) {
  return (unsigned long long)f2bf(a)
       | ((unsigned long long)f2bf(b) << 16)
       | ((unsigned long long)f2bf(c) << 32)
       | ((unsigned long long)f2bf(d) << 48);
}

union FragU { short8 v; uint4 u; unsigned w[4]; };

// Grid = 64 WGs x 320 threads (5 waves). blockIdx<32: layer-0 producer; else
// layer-1 consumer (same bg). Compute waves 0-3 (wave w -> u-cols [16w,16w+16)):
// MFMA M rows = b*4+q, N = u16, 4 accumulator sets (one per gate) -> LSTM update
// fully in-lane, zero shuffles, one barrier/iter. Bias in acc init; x-term = 1
// MFMA per gate from packed-bf16 x in LDS.
// Helper wave 4: per-iter projection of h[i-1] via MFMA (producer), results held
// in LDS; mailbox BATCHED by KB_=8 -> one publish drain / one parallel 32-lane
// poll per 8 iters (amortizes the global round trip that was the R8/R10 floor).
// Producer x: full sequence preloaded to LDS (zero in-loop global loads).
__launch_bounds__(320, 1)
__global__ void qlstm_pipe(const float* __restrict__ x_in,
                           const float* __restrict__ uhr, const float* __restrict__ uhi,
                           const float* __restrict__ uhj, const float* __restrict__ uhk,
                           const float* __restrict__ wxr, const float* __restrict__ wxi,
                           const float* __restrict__ wxj, const float* __restrict__ wxk,
                           const float* __restrict__ wxb_all,
                           const float* __restrict__ fcw_all, const float* __restrict__ fcb_all,
                           float* __restrict__ out_final)
{
  __shared__ unsigned long long sh_xq[T_][4];               // 16 KB x (bf16x4 packed)
  __shared__ __align__(16) unsigned short sh_h[2][4][272];  // 4.25 KB h dbuf
  __shared__ unsigned long long sh_hold[KB_][4];            // 256 B held projections

  const int t    = threadIdx.x;
  const int role = blockIdx.x >> 5;
  const int bg   = blockIdx.x & 31;
  const int bg0  = bg * 4;
  const int lyr  = role;
  const int wv   = t >> 6;
  const int lane = t & 63;
  const int quad = lane >> 4;
  const int sub  = lane & 15;

  for (int i = t; i < 2 * 4 * 272; i += 320) ((unsigned short*)sh_h)[i] = 0;

  if (role == 0) {
    // preload full x sequence (packed bf16x4) into LDS
    for (int idx = t; idx < T_ * 4; idx += 320) {
      const int s = idx & (T_ - 1), b = idx >> 9;
      float4 xv = *(const float4*)(x_in + (size_t)((bg0 + b) * T_ + s) * F_);
      sh_xq[s][b] = pack4bf(xv.x, xv.y, xv.z, xv.w);
    }
  }

  if (wv == 4) {
    // ================= HELPER WAVE =================
    // fw^T A-frags: A[m=f][k] = fw[k][f], rows 4-15 zero
    const float* fw = fcw_all + lyr * H_ * F_;
    const float* fb = fcb_all + lyr * F_;
    FragU Af[8];
    #pragma unroll
    for (int ks = 0; ks < 8; ++ks) {
      FragU f;
      #pragma unroll
      for (int j = 0; j < 8; ++j) {
        const int k = ks * 32 + quad * 8 + j;
        f.v[j] = (sub < 4) ? (short)f2bf(fw[k * 4 + sub]) : (short)0;
      }
      Af[ks] = f;
    }
    const float fb0 = fb[0], fb1 = fb[1], fb2 = fb[2], fb3 = fb[3];
    const int bl = sub & 3;

    if (role == 1) {
      // consumer prologue: poll slots [0,16): lane -> slot lane>>2, batch lane&3
      const int slot = lane >> 2, b = lane & 3;
      unsigned long long v;
      while ((v = __hip_atomic_load(&g_mbq[slot][bg0 + b], __ATOMIC_RELAXED,
                                    __HIP_MEMORY_SCOPE_AGENT)) == 0ull)
        __builtin_amdgcn_s_sleep(1);
      sh_xq[slot][b] = v;
    }
    __syncthreads();

    for (int i = 0; i <= T_; ++i) {
      if (role == 0) {
        if (i >= 1) {                      // projection of h[i-1]
          const char* hp = (const char*)sh_h + ((i + 1) & 1) * 2176;
          f32x4 pa = {fb0, fb1, fb2, fb3};
          #pragma unroll
          for (int ks = 0; ks < 8; ++ks) {
            FragU Bh;
            Bh.u = *(const uint4*)(hp + bl * 544 + ((ks * 32 + quad * 8) << 1));
            pa = __builtin_amdgcn_mfma_f32_16x16x32_bf16(Af[ks].v, Bh.v, pa, 0, 0, 0);
          }
          if (lane < 4) {
            float p0 = pa[0], p1 = pa[1], p2 = pa[2], p3 = pa[3];
            float inv = 1.f / fmaxf(sqrtf(p0*p0 + p1*p1 + p2*p2 + p3*p3), 1e-12f);
            sh_hold[(i - 1) & (KB_ - 1)][lane] = pack4bf(p0*inv, p1*inv, p2*inv, p3*inv);
          }
          if ((i & (KB_ - 1)) == 0 && lane < 32) {   // publish [i-8, i): 1 store/lane
            const int slot = i - KB_ + (lane >> 2), b = lane & 3;
            __hip_atomic_store(&g_mbq[slot][bg0 + b], sh_hold[slot & (KB_ - 1)][b],
                               __ATOMIC_RELAXED, __HIP_MEMORY_SCOPE_AGENT);
          }
        }
      } else {
        if ((i & (KB_ - 1)) == 0 && i >= KB_ && lane < 32) {  // poll [i+8, i+16)
          const int slot = i + KB_ + (lane >> 2), b = lane & 3;
          if (slot < T_) {
            unsigned long long v;
            while ((v = __hip_atomic_load(&g_mbq[slot][bg0 + b], __ATOMIC_RELAXED,
                                          __HIP_MEMORY_SCOPE_AGENT)) == 0ull)
              __builtin_amdgcn_s_sleep(1);
            sh_xq[slot][b] = v;
          }
        }
        if (i == T_) {                     // final projection -> output
          const char* hp = (const char*)sh_h + ((T_ - 1) & 1) * 2176;
          f32x4 pa = {fb0, fb1, fb2, fb3};
          #pragma unroll
          for (int ks = 0; ks < 8; ++ks) {
            FragU Bh;
            Bh.u = *(const uint4*)(hp + bl * 544 + ((ks * 32 + quad * 8) << 1));
            pa = __builtin_amdgcn_mfma_f32_16x16x32_bf16(Af[ks].v, Bh.v, pa, 0, 0, 0);
          }
          if (lane < 4) {
            float p0 = pa[0], p1 = pa[1], p2 = pa[2], p3 = pa[3];
            float inv = 1.f / fmaxf(sqrtf(p0*p0 + p1*p1 + p2*p2 + p3*p3), 1e-12f);
            *(float4*)(out_final + (bg0 + lane) * F_) =
                make_float4(p0 * inv, p1 * inv, p2 * inv, p3 * inv);
          }
        }
      }
      __syncthreads();
    }
  } else {
    // ================= COMPUTE WAVES =================
    const int u  = wv * 16 + sub;   // B n-col / D col
    const int ba = sub >> 2;        // A-side row -> batch
    const int qa = sub & 3;         // A-side row -> q

    FragU Bf[32], Bx[4];
    float bv[4][4];
    {
      const float* Cc[4] = {uhr, uhi, uhj, uhk};
      const float* Xc[4] = {wxr, wxi, wxj, wxk};
      const float* wb = wxb_all + lyr * 4 * H_;
      #pragma unroll
      for (int g = 0; g < 4; ++g) {
        #pragma unroll
        for (int ks = 0; ks < 8; ++ks) {
          const int d  = ks >> 1;
          const int pp = (ks & 1) * 32 + quad * 8;
          const float* src = Cc[d] + (size_t)((lyr * 4 + g) * 64 + pp) * 64 + u;
          FragU f;
          #pragma unroll
          for (int j = 0; j < 8; ++j) f.v[j] = (short)f2bf(src[j * 64]);
          Bf[g * 8 + ks] = f;
        }
        FragU fx; fx.w[0] = 0; fx.w[1] = 0; fx.w[2] = 0; fx.w[3] = 0;
        if (quad == 0) {
          unsigned e0 = f2bf(Xc[0][(lyr * 4 + g) * 64 + u]);
          unsigned e1 = f2bf(Xc[1][(lyr * 4 + g) * 64 + u]);
          unsigned e2 = f2bf(Xc[2][(lyr * 4 + g) * 64 + u]);
          unsigned e3 = f2bf(Xc[3][(lyr * 4 + g) * 64 + u]);
          fx.w[0] = e0 | (e1 << 16);
          fx.w[1] = e2 | (e3 << 16);
        }
        Bx[g] = fx;
        #pragma unroll
        for (int r = 0; r < 4; ++r) bv[g][r] = wb[g * 256 + r * 64 + u];
      }
    }
    unsigned smask[4], smx[4];
    int xsh[4], aoff[8];
    #pragma unroll
    for (int d = 0; d < 4; ++d) {
      const int a = qa ^ d;
      const bool neg = (QSIGN_MASK >> (a * 4 + qa)) & 1;
      smask[d] = neg ? 0x80008000u : 0u;
      smx[d]   = neg ? 0x8000u : 0u;
      xsh[d]   = 16 * a;
    }
    #pragma unroll
    for (int ks = 0; ks < 8; ++ks)
      aoff[ks] = ba * 544 + (((qa ^ (ks >> 1)) * 64 + (ks & 1) * 32 + quad * 8) << 1);

    float cs[4] = {0.f, 0.f, 0.f, 0.f};
    char* hbase = (char*)sh_h;
    __syncthreads();

    for (int i = 0; i <= T_; ++i) {
      if (i < T_) {
        const char* hp = hbase + ((i + 1) & 1) * 2176;   // h[i-1]
        unsigned long long xq = sh_xq[i][ba];
        FragU Ax; Ax.w[0] = 0; Ax.w[1] = 0; Ax.w[2] = 0; Ax.w[3] = 0;
        if (quad == 0) {
          unsigned e0 = ((unsigned)(xq >> xsh[0]) & 0xffffu) ^ smx[0];
          unsigned e1 = ((unsigned)(xq >> xsh[1]) & 0xffffu) ^ smx[1];
          unsigned e2 = ((unsigned)(xq >> xsh[2]) & 0xffffu) ^ smx[2];
          unsigned e3 = ((unsigned)(xq >> xsh[3]) & 0xffffu) ^ smx[3];
          Ax.w[0] = e0 | (e1 << 16);
          Ax.w[1] = e2 | (e3 << 16);
        }
        f32x4 acc0 = {bv[0][0], bv[0][1], bv[0][2], bv[0][3]};
        f32x4 acc1 = {bv[1][0], bv[1][1], bv[1][2], bv[1][3]};
        f32x4 acc2 = {bv[2][0], bv[2][1], bv[2][2], bv[2][3]};
        f32x4 acc3 = {bv[3][0], bv[3][1], bv[3][2], bv[3][3]};
        acc0 = __builtin_amdgcn_mfma_f32_16x16x32_bf16(Ax.v, Bx[0].v, acc0, 0, 0, 0);
        acc1 = __builtin_amdgcn_mfma_f32_16x16x32_bf16(Ax.v, Bx[1].v, acc1, 0, 0, 0);
        acc2 = __builtin_amdgcn_mfma_f32_16x16x32_bf16(Ax.v, Bx[2].v, acc2, 0, 0, 0);
        acc3 = __builtin_amdgcn_mfma_f32_16x16x32_bf16(Ax.v, Bx[3].v, acc3, 0, 0, 0);
        #pragma unroll
        for (int ks = 0; ks < 8; ++ks) {
          FragU A;
          A.u = *(const uint4*)(hp + aoff[ks]);
          const unsigned m = smask[ks >> 1];
          A.w[0] ^= m; A.w[1] ^= m; A.w[2] ^= m; A.w[3] ^= m;
          acc0 = __builtin_amdgcn_mfma_f32_16x16x32_bf16(A.v, Bf[0 * 8 + ks].v, acc0, 0, 0, 0);
          acc1 = __builtin_amdgcn_mfma_f32_16x16x32_bf16(A.v, Bf[1 * 8 + ks].v, acc1, 0, 0, 0);
          acc2 = __builtin_amdgcn_mfma_f32_16x16x32_bf16(A.v, Bf[2 * 8 + ks].v, acc2, 0, 0, 0);
          acc3 = __builtin_amdgcn_mfma_f32_16x16x32_bf16(A.v, Bf[3 * 8 + ks].v, acc3, 0, 0, 0);
        }
        // fully in-lane gates: b=quad, col = r*64+u
        char* hw = hbase + (i & 1) * 2176 + quad * 544;
        #pragma unroll
        for (int r = 0; r < 4; ++r) {
          float fg = fast_sigmoid(acc0[r]);
          float ig = fast_sigmoid(acc1[r]);
          float og = fast_sigmoid(acc2[r]);
          float cv = fast_tanh(acc3[r]);
          cs[r] = ig * cv + fg * cs[r];
          float h = og * fast_tanh(cs[r]);
          *(unsigned short*)(hw + ((r * 64 + u) << 1)) = (unsigned short)f2bf(h);
        }
      }
      __syncthreads();
    }
  }
}

extern "C" void kernel_launch(void* const* d_in, const int* in_sizes, int n_in,
                              void* d_out, int out_size, void* d_ws, size_t ws_size,
                              hipStream_t stream) {
  const float* x   = (const float*)d_in[0];
  const float* wxr = (const float*)d_in[1];
  const float* wxi = (const float*)d_in[2];
  const float* wxj = (const float*)d_in[3];
  const float* wxk = (const float*)d_in[4];
  const float* wxb = (const float*)d_in[5];
  const float* uhr = (const float*)d_in[6];
  const float* uhi = (const float*)d_in[7];
  const float* uhj = (const float*)d_in[8];
  const float* uhk = (const float*)d_in[9];
  const float* fcw = (const float*)d_in[10];
  const float* fcb = (const float*)d_in[11];
  float* out = (float*)d_out;

  zero_mb<<<dim3(T_ * B_ / 256), dim3(256), 0, stream>>>();
  qlstm_pipe<<<dim3(64), dim3(320), 0, stream>>>(
      x, uhr, uhi, uhj, uhk, wxr, wxi, wxj, wxk, wxb, fcw, fcb, out);
}